// Round 4
// baseline (85.191 us; speedup 1.0000x reference)
//
#include <hip/hip_runtime.h>

// ToeplitzMemoryProjection (HiPPO LagT, alpha=0.5 bilinear).
//
// Math: with c = 1 + 0.25*dt, g = (1-0.25*dt)/c, beta = dt*u/c, the step
// operator is (g*I - S)(I - g*S)^{-1} (S = down-shift) and the input term is
// beta*(I - g*S)^{-1} e0. Multiplying the scan x_l = A_l x_{l-1} + B_l by
// (I - g_l S) (exact in the truncated lower-tri Toeplitz algebra) gives the
// O(N)-per-step recurrence
//
//   x_l[i] = g_l*(x_l[i-1] + x_{l-1}[i]) - x_{l-1}[i-1] + beta_l*[i==0]
//
// Lane-skewed wavefront: 1 block per channel (256 ch), 256 threads (col = tid),
// thread i handles row l at tick T = l + wave*SKEW + lane.
//   - x_l[i-1] via DPP wave_shr:1 (VALU-latency lane shift, lane0 -> 0)
//   - cross-wave handoff: lane0 reads left wave's ring column 63 directly
//     (written >= 1 barrier-chunk earlier; SKEW-63 = 33 > KCH - 1)
//   - ring slots are TICK-indexed (slot = t & 127, wave-uniform)
//   - REGISTER STAGING (round-4 fix): the chunk's 32 per-lane g values and the
//     flush's 32 ring values are prefetched into statically-indexed register
//     arrays so the ds_reads issue back-to-back (ILP) instead of the
//     read->waitcnt->use serialization the 24-VGPR build had. At 1 wave/SIMD
//     there is no TLP; ILP is the only latency cover.
//   - barriers are LDS-only (s_waitcnt lgkmcnt(0) + s_barrier, no vmcnt
//     drain): the nontemporal HBM store stream stays in flight across chunks.
//   - completed rows flushed as coalesced 256 B nontemporal row-segment stores

namespace {

constexpr int LLEN  = 1024;              // L
constexpr int NCHAN = 256;               // B*M
constexpr int NWAVE = 4;                 // waves per block (N = 256 cols)
constexpr int KCH   = 32;                // ticks per chunk (barrier period)
constexpr int SKEW  = 64 + KCH;          // per-wave tick offset (96); SKEW-63=33>KCH-1
constexpr int RINGT = 128;               // tick-indexed ring slots per wave (pow2)
constexpr int LAST_T = (LLEN - 1) + 255 + (NWAVE - 1) * KCH;  // 1374
constexpr int NCHUNK = LAST_T / KCH + 1; // 43

constexpr int G_OFF = 0;
constexpr int B_OFF = LLEN;
constexpr int R_OFF = 2 * LLEN;
constexpr int LDS_FLOATS = R_OFF + NWAVE * RINGT * 64;
constexpr size_t LDS_BYTES = (size_t)LDS_FLOATS * sizeof(float);  // 139264 B

__device__ __forceinline__ float dpp_wave_shr1(float v) {
    // v_mov_b32_dpp wave_shr:1 — lane i gets lane i-1's value, lane 0 gets `old`=0.
    return __int_as_float(__builtin_amdgcn_update_dpp(
        0, __float_as_int(v), 0x138 /*WAVE_SHR1*/, 0xF, 0xF, false));
}

// LDS-only barrier: order ring ds_writes/ds_reads across waves WITHOUT
// draining the global store queue (vmcnt untouched).
__device__ __forceinline__ void lds_barrier() {
    __builtin_amdgcn_sched_barrier(0);
    asm volatile("s_waitcnt lgkmcnt(0)" ::: "memory");
    __builtin_amdgcn_s_barrier();
    __builtin_amdgcn_sched_barrier(0);
}

// One KCH-tick chunk of the wavefront recurrence.
// hb[s]: for W0 (wave 0) the beta values b_arr[T0+s] (used by lane 0);
//        for other waves the left wave's column-63 x values (used by lane 0).
template <bool W0, bool MASKED>
__device__ __forceinline__ void do_chunk(
    int T0, int base_l, int lane, bool lane0,
    const float* __restrict__ g_arr, const float (&hb)[KCH],
    float* __restrict__ my_ring, float& prev_own, float& prev_left)
{
    // ---- register-stage this chunk's g values (32 independent ds_reads) ----
    // lane's addresses are consecutive: g_arr[base_l - lane + s], s=0..KCH-1
    float gpre[KCH];
    #pragma unroll
    for (int s = 0; s < KCH; ++s) {
        int l = base_l + s - lane;
        if (MASKED) l = min(max(l, 0), LLEN - 1);
        gpre[s] = g_arr[l];
    }

    const int rb = ((T0 & (RINGT - 1)) << 6) + lane;  // never wraps mid-chunk
    #pragma unroll
    for (int s = 0; s < KCH; ++s) {
        float cl = dpp_wave_shr1(prev_own);
        const float sel = lane0 ? hb[s] : 0.0f;
        if (!W0) cl = cl + sel;                       // lane0: left wave handoff
        const float cterm = W0 ? (sel - prev_left)    // lane0: +beta
                               : (0.0f - prev_left);
        const float x = fmaf(gpre[s], cl, fmaf(gpre[s], prev_own, cterm));
        my_ring[rb + (s << 6)] = x;                   // garbage for OOB rows is
                                                      // never flushed: harmless
        if (MASKED) {
            const int l = base_l + s - lane;
            const bool act = (l >= 0) & (l < LLEN);
            prev_left = act ? cl : prev_left;
            prev_own  = act ? x  : prev_own;
        } else {
            prev_left = cl;
            prev_own  = x;
        }
    }
}

__global__ __launch_bounds__(256, 1)
void toeplitz_scan(const float* __restrict__ vin,   // inputs (L, 256)
                   const float* __restrict__ dtin,  // dt     (L, 256)
                   float* __restrict__ out)         // (L, 256, 256)
{
    extern __shared__ float lds[];
    float* g_arr = lds + G_OFF;   // [LLEN]
    float* b_arr = lds + B_OFF;   // [LLEN]
    float* ring  = lds + R_OFF;   // [NWAVE][RINGT][64], tick-indexed slots

    const int ch   = blockIdx.x;
    const int tid  = threadIdx.x;
    const int wave = tid >> 6;
    const int lane = tid & 63;

    // ---- precompute g[l], beta[l] for this channel ----
    #pragma unroll
    for (int k = 0; k < LLEN / 256; ++k) {
        const int l = tid + k * 256;
        const float d = dtin[l * NCHAN + ch];
        const float u = vin[l * NCHAN + ch];
        const float inv_c = 1.0f / (1.0f + 0.25f * d);
        g_arr[l] = (1.0f - 0.25f * d) * inv_c;
        b_arr[l] = d * u * inv_c;
    }
    __syncthreads();

    float* my_ring = ring + wave * (RINGT * 64);
    const float* lf_ring = ring + (wave - 1) * (RINGT * 64);  // valid for wave>0

    const int wskew  = wave * SKEW;
    const bool w0    = (wave == 0);
    const bool lane0 = (lane == 0);

    float prev_own = 0.0f, prev_left = 0.0f;
    int nf = 0;                                   // next row to flush
    float* outp = out + (ch * 256 + wave * 64 + lane);  // +65536 per row

    for (int c = 0; c < NCHUNK; ++c) {
        const int T0 = c * KCH;
        const int base_l = T0 - wskew;            // lane0's row at s=0
        const bool any_act = (base_l >= -(KCH - 1)) && (base_l <= LLEN - 1 + 63);

        if (any_act) {
            const bool all_act = (base_l >= 63) && (base_l <= LLEN - KCH);
            float hb[KCH];
            if (w0) {
                if (all_act) {
                    #pragma unroll
                    for (int q = 0; q < KCH / 4; ++q) {
                        const float4 t =
                            *reinterpret_cast<const float4*>(&b_arr[T0 + 4 * q]);
                        hb[4*q+0] = t.x; hb[4*q+1] = t.y;
                        hb[4*q+2] = t.z; hb[4*q+3] = t.w;
                    }
                } else {
                    #pragma unroll
                    for (int s = 0; s < KCH; ++s)
                        hb[s] = b_arr[min(T0 + s, LLEN - 1)];
                }
                if (all_act)
                    do_chunk<true, false>(T0, base_l, lane, lane0, g_arr, hb,
                                          my_ring, prev_own, prev_left);
                else
                    do_chunk<true, true>(T0, base_l, lane, lane0, g_arr, hb,
                                         my_ring, prev_own, prev_left);
            } else {
                // left wave's lane-63 values: slot (T0+s-33) & 127, col 63.
                // Written >= 1 barrier-chunk ago; overwritten only at
                // tick+128 (>= 3 chunks later). Independent broadcast reads.
                float hb2[KCH];
                #pragma unroll
                for (int s = 0; s < KCH; ++s) {
                    const int slot = (T0 + s - (SKEW - 63)) & (RINGT - 1);
                    hb2[s] = lf_ring[(slot << 6) + 63];
                }
                if (all_act)
                    do_chunk<false, false>(T0, base_l, lane, lane0, g_arr, hb2,
                                           my_ring, prev_own, prev_left);
                else
                    do_chunk<false, true>(T0, base_l, lane, lane0, g_arr, hb2,
                                          my_ring, prev_own, prev_left);
            }
        }

        // ---- flush rows whose lane-63 value landed by tick T0+KCH-1 ----
        {
            const int hi = min(base_l + KCH - 64, LLEN - 1);
            if (hi - nf == KCH - 1) {             // steady state: exactly KCH rows
                // batch: 32 independent ring reads into registers, THEN stores
                float tmp[KCH];
                #pragma unroll
                for (int q = 0; q < KCH; ++q) {
                    const int slot = (nf + q + wskew + lane) & (RINGT - 1);
                    tmp[q] = my_ring[(slot << 6) + lane];
                }
                #pragma unroll
                for (int q = 0; q < KCH; ++q) {
                    __builtin_nontemporal_store(tmp[q], outp);
                    outp += NCHAN * 256;
                }
                nf += KCH;
            } else {
                for (; nf <= hi; ++nf) {
                    const int slot = (nf + wskew + lane) & (RINGT - 1);
                    __builtin_nontemporal_store(my_ring[(slot << 6) + lane], outp);
                    outp += NCHAN * 256;
                }
            }
        }
        lds_barrier();
    }

    // safety drain (normally empty)
    for (; nf < LLEN; ++nf) {
        const int slot = (nf + wskew + lane) & (RINGT - 1);
        __builtin_nontemporal_store(my_ring[(slot << 6) + lane], outp);
        outp += NCHAN * 256;
    }
}

} // namespace

extern "C" void kernel_launch(void* const* d_in, const int* in_sizes, int n_in,
                              void* d_out, int out_size, void* d_ws, size_t ws_size,
                              hipStream_t stream) {
    (void)in_sizes; (void)n_in; (void)d_ws; (void)ws_size; (void)out_size;
    const float* vin  = (const float*)d_in[0];   // "inputs"
    const float* dtin = (const float*)d_in[1];   // "dt"
    float* out = (float*)d_out;

    (void)hipFuncSetAttribute(reinterpret_cast<const void*>(toeplitz_scan),
                              hipFuncAttributeMaxDynamicSharedMemorySize,
                              (int)LDS_BYTES);

    toeplitz_scan<<<NCHAN, 256, LDS_BYTES, stream>>>(vin, dtin, out);
}